// Round 6
// baseline (2173.970 us; speedup 1.0000x reference)
//
#include <hip/hip_runtime.h>
#include <math.h>

#define NN 10000
#define NE 40000
#define NGRAPH 64
#define HID 64
#define EDIM 16
#define NLAYERS 3

// ---- fused message kernel geometry (v6: o-dense, 2-pass B to avoid spill) ----
#define GNODES 8
#define NGROUPS (NN / GNODES)       // 1250
#define MSG_THREADS 1024            // 16 waves, 1 block/CU (136KB LDS)
#define HSTR 12                     // h_s row stride: float4-aligned, bank-spread
#define B_FLOATS (GNODES * 64 * 64) // 32768 floats = 128 KB
#define HS_FLOATS (64 * HSTR)       // 768
#define CS_FLOATS (GNODES * 64)     // 512
#define MSG_LDS_FLOATS (B_FLOATS + HS_FLOATS + CS_FLOATS)   // 34048 = 136192 B

__device__ __forceinline__ float silu_f(float x) { return x / (1.f + expf(-x)); }

// ---------------- small row GEMM: out[M][64] = act(A[M][K] @ W[K][64] + bias) ----
template<int K, bool DO_SILU, bool HAS_BIAS>
__global__ __launch_bounds__(256)
void k_rowmm(const float* __restrict__ A, const float* __restrict__ W,
             const float* __restrict__ bias, float* __restrict__ out, int M) {
    __shared__ float Ws[K * 64];
    __shared__ float As[4 * K];
    const int tid = threadIdx.x;
    for (int idx = tid; idx < K * 64; idx += 256) Ws[idx] = W[idx];
    const int r0 = blockIdx.x * 4;
    for (int idx = tid; idx < 4 * K; idx += 256) {
        int r = r0 + idx / K;
        As[idx] = (r < M) ? A[(size_t)r * K + (idx % K)] : 0.f;
    }
    __syncthreads();
    const int rr = tid >> 6, c = tid & 63;
    const int r = r0 + rr;
    if (r >= M) return;
    float s = HAS_BIAS ? bias[c] : 0.f;
#pragma unroll
    for (int k = 0; k < K; k++) s += As[rr * K + k] * Ws[k * 64 + c];
    if (DO_SILU) s = silu_f(s);
    out[(size_t)r * 64 + c] = s;
}

// ---------------- degree histograms (src + dst) ----------------
__global__ void k_hist(const int* __restrict__ ei, int* __restrict__ cnt_s,
                       int* __restrict__ cnt_d) {
    int e = blockIdx.x * 256 + threadIdx.x;
    if (e >= NE) return;
    atomicAdd(&cnt_s[ei[e]], 1);
    atomicAdd(&cnt_d[ei[NE + e]], 1);
}

__global__ void k_invdeg(const int* __restrict__ cnt_d, float* __restrict__ invd) {
    int n = blockIdx.x * 256 + threadIdx.x;
    if (n < NN) {
        int d = cnt_d[n];
        invd[n] = (d > 0) ? 1.f / (float)d : 0.f;
    }
}

// ---------------- single-block exclusive scan over NN counts ----------------
__global__ __launch_bounds__(1024)
void k_scan(const int* __restrict__ cnt, int* __restrict__ off, int* __restrict__ cur) {
    __shared__ int part[1024];
    const int t = threadIdx.x;
    const int CH = (NN + 1023) / 1024;  // 10
    const int base0 = t * CH;
    int s = 0;
    for (int i = 0; i < CH; i++) {
        int idx = base0 + i;
        if (idx < NN) s += cnt[idx];
    }
    part[t] = s;
    __syncthreads();
    for (int d = 1; d < 1024; d <<= 1) {
        int v = (t >= d) ? part[t - d] : 0;
        __syncthreads();
        part[t] += v;
        __syncthreads();
    }
    int run = (t == 0) ? 0 : part[t - 1];
    for (int i = 0; i < CH; i++) {
        int idx = base0 + i;
        if (idx < NN) {
            off[idx] = run;
            run += cnt[idx];
            cur[idx] = 0;
        }
    }
    if (t == 1023) off[NN] = run;
}

__global__ void k_fill(const int* __restrict__ keys, const int* __restrict__ off,
                       int* __restrict__ cur, int* __restrict__ eid) {
    int e = blockIdx.x * 256 + threadIdx.x;
    if (e >= NE) return;
    int s = keys[e];
    int p = atomicAdd(&cur[s], 1);
    eid[off[s] + p] = e;
}

// ---------------- fused B-compute + C-compute + message store (v6) ----------------
// Block = group of 8 src nodes, full o=64. B computed in TWO k-half passes so the
// live accumulator set is 16 (v5's 32+8 exceeded the allocator's 40-reg grant and
// spilled to scratch -> 12x slowdown).
__global__ __launch_bounds__(MSG_THREADS, 4)
void k_msg(const float* __restrict__ h, const float* __restrict__ g,
           const float* __restrict__ w2, const float* __restrict__ b2,
           const int* __restrict__ csr_off, const int* __restrict__ csr_eid,
           float* __restrict__ msg) {
    extern __shared__ float lds[];
    float* Bl  = lds;                         // [8 j][64 k][64 o] linear
    float* h_s = lds + B_FLOATS;              // [64 i][stride 12]
    float* C_s = lds + B_FLOATS + HS_FLOATS;  // [8 j][64 o]
    __shared__ int offs[GNODES + 1];

    const int tid = threadIdx.x;
    const int n0  = blockIdx.x * GNODES;
    const int o   = tid & 63;
    const int kc  = tid >> 6;     // 0..15

    // stage h transposed: wave j loads row n0+j coalesced (256B), writes col j
    if (tid < GNODES * 64) {
        const int j = tid >> 6, i = tid & 63;
        h_s[i * HSTR + j] = h[(size_t)(n0 + j) * 64 + i];
    }
    if (tid <= GNODES) offs[tid] = csr_off[n0 + tid];
    __syncthreads();

    // ---- B phase: two k-half passes, thread (kc,o) owns k = p*32 + kc*2 + {0,1} ----
#pragma unroll
    for (int p = 0; p < 2; ++p) {
        const int k0 = p * 32 + kc * 2;
        const float* w2p = w2 + (size_t)k0 * 4096 + o;   // dense 256B wave loads
        float acc0[8], acc1[8];
#pragma unroll
        for (int j = 0; j < 8; ++j) { acc0[j] = 0.f; acc1[j] = 0.f; }
#pragma unroll 4
        for (int i = 0; i < 64; ++i) {
            const float w0 = w2p[i * 64];
            const float w1 = w2p[i * 64 + 4096];
            const float4 ha = *(const float4*)(h_s + i * HSTR);      // broadcast
            const float4 hb = *(const float4*)(h_s + i * HSTR + 4);
            acc0[0] += w0 * ha.x; acc0[1] += w0 * ha.y; acc0[2] += w0 * ha.z; acc0[3] += w0 * ha.w;
            acc0[4] += w0 * hb.x; acc0[5] += w0 * hb.y; acc0[6] += w0 * hb.z; acc0[7] += w0 * hb.w;
            acc1[0] += w1 * ha.x; acc1[1] += w1 * ha.y; acc1[2] += w1 * ha.z; acc1[3] += w1 * ha.w;
            acc1[4] += w1 * hb.x; acc1[5] += w1 * hb.y; acc1[6] += w1 * hb.z; acc1[7] += w1 * hb.w;
        }
#pragma unroll
        for (int j = 0; j < 8; ++j) {
            Bl[j * 4096 + k0 * 64 + o]       = acc0[j];
            Bl[j * 4096 + (k0 + 1) * 64 + o] = acc1[j];
        }
    }

    // ---- C phase (512 threads): C_s[j][o] = sum_i h[j,i] * b2[i*64+o] ----
    if (tid < GNODES * 64) {
        const int j = tid >> 6;
        const float* bp = b2 + o;
        float c = 0.f;
#pragma unroll 8
        for (int i = 0; i < 64; ++i) c += h_s[i * HSTR + j] * bp[i * 64];
        C_s[j * 64 + o] = c;
    }
    __syncthreads();

    // ---- edge phase: task = (edge slot) x (o4 of 16B); 64 slots/pass ----
    const float4* Bl4 = (const float4*)Bl;
    const float4* Cs4 = (const float4*)C_s;
    const int P0 = offs[0];
    const int Etot = offs[GNODES] - P0;
    const int o4 = tid & 15;
    for (int slot = tid >> 4; slot < Etot; slot += 64) {
        const int gpos = P0 + slot;
        int j = 0;
#pragma unroll
        for (int q = 1; q < GNODES; ++q) j += (gpos >= offs[q]) ? 1 : 0;
        const int e = csr_eid[gpos];
        const float* grow = g + (size_t)e * 64;
        const float4* BjRow = Bl4 + j * 1024 + o4;

        float4 m0 = Cs4[j * 16 + o4];
        float4 m1 = {0.f, 0.f, 0.f, 0.f};
#pragma unroll
        for (int k4 = 0; k4 < 16; ++k4) {
            const float4 g4 = *(const float4*)(grow + k4 * 4);
            const float4 b0 = BjRow[(k4 * 4 + 0) * 16];
            const float4 b1 = BjRow[(k4 * 4 + 1) * 16];
            const float4 b2v = BjRow[(k4 * 4 + 2) * 16];
            const float4 b3 = BjRow[(k4 * 4 + 3) * 16];
            m0.x += g4.x * b0.x; m0.y += g4.x * b0.y; m0.z += g4.x * b0.z; m0.w += g4.x * b0.w;
            m1.x += g4.y * b1.x; m1.y += g4.y * b1.y; m1.z += g4.y * b1.z; m1.w += g4.y * b1.w;
            m0.x += g4.z * b2v.x; m0.y += g4.z * b2v.y; m0.z += g4.z * b2v.z; m0.w += g4.z * b2v.w;
            m1.x += g4.w * b3.x; m1.y += g4.w * b3.y; m1.z += g4.w * b3.z; m1.w += g4.w * b3.w;
        }
        const float4 m = make_float4(m0.x + m1.x, m0.y + m1.y, m0.z + m1.z, m0.w + m1.w);
        *(float4*)(msg + (size_t)e * 64 + o4 * 4) = m;
    }
}

// ---------------- gather by dst + root GEMM + silu ----------------
__global__ __launch_bounds__(256)
void k_aggfin(const float* __restrict__ h, const float* __restrict__ msg,
              const int* __restrict__ off2, const int* __restrict__ eid2,
              const float* __restrict__ invd, const float* __restrict__ rw,
              const float* __restrict__ cb, float* __restrict__ hout) {
    __shared__ float Ws[64 * 64];
    __shared__ float As[4 * 64];
    __shared__ int eoff[5];
    const int tid = threadIdx.x;
    for (int idx = tid; idx < 64 * 64; idx += 256) Ws[idx] = rw[idx];
    const int r0 = blockIdx.x * 4;
    As[tid] = h[(size_t)r0 * 64 + tid];
    if (tid < 5) eoff[tid] = off2[r0 + tid];
    __syncthreads();
    const int rr = tid >> 6, c = tid & 63;
    const int r = r0 + rr;
    float a = 0.f;
    for (int p = eoff[rr]; p < eoff[rr + 1]; ++p) {
        const int e = eid2[p];
        a += msg[(size_t)e * 64 + c];
    }
    float s = cb[c] + a * invd[r];
#pragma unroll
    for (int k = 0; k < 64; k++) s += As[rr * 64 + k] * Ws[k * 64 + c];
    hout[(size_t)r * 64 + c] = silu_f(s);
}

// ---------------- global mean pool (accumulate) ----------------
__global__ void k_pool(const float* __restrict__ h, const int* __restrict__ batch,
                       float* __restrict__ hg, float* __restrict__ gcnt) {
    int idx = blockIdx.x * 256 + threadIdx.x;
    if (idx >= NN * 64) return;
    int n = idx >> 6, o = idx & 63;
    int b = batch[n];
    atomicAdd(&hg[b * 64 + o], h[idx]);
    if (o == 0) atomicAdd(&gcnt[b], 1.f);
}

// ---------------- head MLP ----------------
__global__ __launch_bounds__(64)
void k_head(const float* __restrict__ hg, const float* __restrict__ gcnt,
            const float* __restrict__ w1, const float* __restrict__ b1,
            const float* __restrict__ w2, const float* __restrict__ b2,
            float* __restrict__ out) {
    __shared__ float hrow[64];
    const int gidx = blockIdx.x, t = threadIdx.x;
    const float inv = 1.f / fmaxf(gcnt[gidx], 1.f);
    hrow[t] = hg[gidx * 64 + t] * inv;
    __syncthreads();
    float s = b1[t];
#pragma unroll
    for (int k = 0; k < 64; k++) s += hrow[k] * w1[k * 64 + t];
    s = silu_f(s);
    float v = s * w2[t];
#pragma unroll
    for (int d = 32; d > 0; d >>= 1) v += __shfl_down(v, d);
    if (t == 0) out[gidx] = v + b2[0];
}

extern "C" void kernel_launch(void* const* d_in, const int* in_sizes, int n_in,
                              void* d_out, int out_size, void* d_ws, size_t ws_size,
                              hipStream_t stream) {
    const float* x     = (const float*)d_in[0];
    const float* ea    = (const float*)d_in[1];
    const int*   ei    = (const int*)  d_in[2];
    const int*   batch = (const int*)  d_in[3];
    const float* pw    = (const float*)d_in[4];
    const float* pb    = (const float*)d_in[5];
    const float* ew1   = (const float*)d_in[6];
    const float* eb1   = (const float*)d_in[7];
    const float* ew2   = (const float*)d_in[8];
    const float* eb2   = (const float*)d_in[9];
    const float* rw    = (const float*)d_in[10];
    const float* cb    = (const float*)d_in[11];
    const float* hw1   = (const float*)d_in[12];
    const float* hb1   = (const float*)d_in[13];
    const float* hw2   = (const float*)d_in[14];
    const float* hb2   = (const float*)d_in[15];
    float* out = (float*)d_out;

    float* ws = (float*)d_ws;
    size_t off = 0;
    auto alloc = [&](size_t n) {
        float* p = ws + off;
        off += (n + 63) & ~(size_t)63;
        return p;
    };
    float* hA   = alloc((size_t)NN * 64);
    float* hBuf = alloc((size_t)NN * 64);
    float* gbuf = alloc((size_t)NE * 64);
    float* msg  = alloc((size_t)NE * 64);
    float* invd = alloc(NN);
    float* hg   = alloc(64 * 64);
    float* gcnt = alloc(64);
    int* off_s = (int*)alloc(NN + 1);
    int* off_d = (int*)alloc(NN + 1);
    int* cnt_s = (int*)alloc(NN);
    int* cnt_d = (int*)alloc(NN);
    int* cur_s = (int*)alloc(NN);
    int* cur_d = (int*)alloc(NN);
    int* eid_s = (int*)alloc(NE);
    int* eid_d = (int*)alloc(NE);

    hipMemsetAsync(cnt_s, 0, NN * sizeof(int), stream);
    hipMemsetAsync(cnt_d, 0, NN * sizeof(int), stream);
    hipMemsetAsync(hg, 0, 64 * 64 * sizeof(float), stream);
    hipMemsetAsync(gcnt, 0, 64 * sizeof(float), stream);

    k_hist<<<dim3((NE + 255) / 256), dim3(256), 0, stream>>>(ei, cnt_s, cnt_d);
    k_invdeg<<<dim3((NN + 255) / 256), dim3(256), 0, stream>>>(cnt_d, invd);
    k_scan<<<dim3(1), dim3(1024), 0, stream>>>(cnt_s, off_s, cur_s);
    k_scan<<<dim3(1), dim3(1024), 0, stream>>>(cnt_d, off_d, cur_d);
    k_fill<<<dim3((NE + 255) / 256), dim3(256), 0, stream>>>(ei, off_s, cur_s, eid_s);
    k_fill<<<dim3((NE + 255) / 256), dim3(256), 0, stream>>>(ei + NE, off_d, cur_d, eid_d);

    // h = x @ proj_w + proj_b
    k_rowmm<64, false, true><<<dim3(NN / 4), dim3(256), 0, stream>>>(x, pw, pb, hA, NN);

    const size_t MSG_LDS_BYTES = (size_t)MSG_LDS_FLOATS * sizeof(float);
    hipFuncSetAttribute(reinterpret_cast<const void*>(k_msg),
                        hipFuncAttributeMaxDynamicSharedMemorySize, (int)MSG_LDS_BYTES);

    float* hcur = hA;
    float* hnxt = hBuf;
    for (int l = 0; l < NLAYERS; l++) {
        // g = silu(edge_attr @ w1 + b1)
        k_rowmm<16, true, true><<<dim3(NE / 4), dim3(256), 0, stream>>>(
            ea, ew1 + (size_t)l * EDIM * 64, eb1 + (size_t)l * 64, gbuf, NE);
        k_msg<<<dim3(NGROUPS), dim3(MSG_THREADS), MSG_LDS_BYTES, stream>>>(
            hcur, gbuf, ew2 + (size_t)l * 64 * 4096, eb2 + (size_t)l * 4096,
            off_s, eid_s, msg);
        k_aggfin<<<dim3(NN / 4), dim3(256), 0, stream>>>(
            hcur, msg, off_d, eid_d, invd, rw + (size_t)l * 64 * 64,
            cb + (size_t)l * 64, hnxt);
        float* t = hcur; hcur = hnxt; hnxt = t;
    }

    k_pool<<<dim3((NN * 64) / 256), dim3(256), 0, stream>>>(hcur, batch, hg, gcnt);
    k_head<<<dim3(NGRAPH), dim3(64), 0, stream>>>(hg, gcnt, hw1, hb1, hw2, hb2, out);
}

// Round 7
// 757.241 us; speedup vs baseline: 2.8709x; 2.8709x over previous
//
#include <hip/hip_runtime.h>
#include <math.h>

#define NN 10000
#define NE 40000
#define NGRAPH 64
#define HID 64
#define EDIM 16
#define NLAYERS 3

// ---- chunked B materialization ----
#define NCH 2500                 // nodes per chunk (4 chunks, exact)
#define NCHUNKS 4
#define MB_BLOCKS ((NCH + 7) / 8)        // 313
#define BCH_ROWS (MB_BLOCKS * 8)         // 2504 rows allocated

__device__ __forceinline__ float silu_f(float x) { return x / (1.f + expf(-x)); }

// ---------------- small row GEMM: out[M][64] = act(A[M][K] @ W[K][64] + bias) ----
template<int K, bool DO_SILU, bool HAS_BIAS>
__global__ __launch_bounds__(256)
void k_rowmm(const float* __restrict__ A, const float* __restrict__ W,
             const float* __restrict__ bias, float* __restrict__ out, int M) {
    __shared__ float Ws[K * 64];
    __shared__ float As[4 * K];
    const int tid = threadIdx.x;
    for (int idx = tid; idx < K * 64; idx += 256) Ws[idx] = W[idx];
    const int r0 = blockIdx.x * 4;
    for (int idx = tid; idx < 4 * K; idx += 256) {
        int r = r0 + idx / K;
        As[idx] = (r < M) ? A[(size_t)r * K + (idx % K)] : 0.f;
    }
    __syncthreads();
    const int rr = tid >> 6, c = tid & 63;
    const int r = r0 + rr;
    if (r >= M) return;
    float s = HAS_BIAS ? bias[c] : 0.f;
#pragma unroll
    for (int k = 0; k < K; k++) s += As[rr * K + k] * Ws[k * 64 + c];
    if (DO_SILU) s = silu_f(s);
    out[(size_t)r * 64 + c] = s;
}

// ---------------- degree histograms (src + dst) ----------------
__global__ void k_hist(const int* __restrict__ ei, int* __restrict__ cnt_s,
                       int* __restrict__ cnt_d) {
    int e = blockIdx.x * 256 + threadIdx.x;
    if (e >= NE) return;
    atomicAdd(&cnt_s[ei[e]], 1);
    atomicAdd(&cnt_d[ei[NE + e]], 1);
}

__global__ void k_invdeg(const int* __restrict__ cnt_d, float* __restrict__ invd) {
    int n = blockIdx.x * 256 + threadIdx.x;
    if (n < NN) {
        int d = cnt_d[n];
        invd[n] = (d > 0) ? 1.f / (float)d : 0.f;
    }
}

// ---------------- single-block exclusive scan over NN counts ----------------
__global__ __launch_bounds__(1024)
void k_scan(const int* __restrict__ cnt, int* __restrict__ off, int* __restrict__ cur) {
    __shared__ int part[1024];
    const int t = threadIdx.x;
    const int CH = (NN + 1023) / 1024;  // 10
    const int base0 = t * CH;
    int s = 0;
    for (int i = 0; i < CH; i++) {
        int idx = base0 + i;
        if (idx < NN) s += cnt[idx];
    }
    part[t] = s;
    __syncthreads();
    for (int d = 1; d < 1024; d <<= 1) {
        int v = (t >= d) ? part[t - d] : 0;
        __syncthreads();
        part[t] += v;
        __syncthreads();
    }
    int run = (t == 0) ? 0 : part[t - 1];
    for (int i = 0; i < CH; i++) {
        int idx = base0 + i;
        if (idx < NN) {
            off[idx] = run;
            run += cnt[idx];
            cur[idx] = 0;
        }
    }
    if (t == 1023) off[NN] = run;
}

__global__ void k_fill(const int* __restrict__ keys, const int* __restrict__ off,
                       int* __restrict__ cur, int* __restrict__ eid) {
    int e = blockIdx.x * 256 + threadIdx.x;
    if (e >= NE) return;
    int s = keys[e];
    int p = atomicAdd(&cur[s], 1);
    eid[off[s] + p] = e;
}

// ---------------- B-chunk GEMM: B[(n-n0), k*64+o] = sum_i h[n,i]*w2[k, i*64+o] ----
// grid (MB_BLOCKS, 16); block 256 = 4 waves; wave -> k = nb*4+w, lane -> o.
// Live set ~24 VGPR by construction (2 named float4 accs), 2KB LDS, 8 waves/SIMD.
__global__ __launch_bounds__(256, 8)
void k_bgemm(const float* __restrict__ h, const float* __restrict__ w2,
             float* __restrict__ B, int n0) {
    __shared__ float h_s[64 * 8];   // [i][r]
    const int tid = threadIdx.x;
    const int mb = blockIdx.x, nb = blockIdx.y;
    const int row0 = n0 + mb * 8;
#pragma unroll
    for (int idx = tid; idx < 512; idx += 256) {
        const int r = idx >> 6, i = idx & 63;
        const int row = row0 + r;
        h_s[i * 8 + r] = (row < NN) ? h[(size_t)row * 64 + i] : 0.f;
    }
    __syncthreads();

    const int k = nb * 4 + (tid >> 6);
    const int o = tid & 63;
    const float* wp = w2 + (size_t)k * 4096 + o;   // dense 256B wave loads
    float4 A0 = {0.f, 0.f, 0.f, 0.f};
    float4 A1 = {0.f, 0.f, 0.f, 0.f};
#pragma unroll 8
    for (int i = 0; i < 64; ++i) {
        const float w = wp[i * 64];
        const float4 ha = *(const float4*)(h_s + i * 8);       // LDS broadcast
        const float4 hb = *(const float4*)(h_s + i * 8 + 4);
        A0.x += w * ha.x; A0.y += w * ha.y; A0.z += w * ha.z; A0.w += w * ha.w;
        A1.x += w * hb.x; A1.y += w * hb.y; A1.z += w * hb.z; A1.w += w * hb.w;
    }
    float* Bp = B + ((size_t)mb * 8) * 4096 + k * 64 + o;      // dense 256B stores
    Bp[0 * 4096] = A0.x; Bp[1 * 4096] = A0.y;
    Bp[2 * 4096] = A0.z; Bp[3 * 4096] = A0.w;
    Bp[4 * 4096] = A1.x; Bp[5 * 4096] = A1.y;
    Bp[6 * 4096] = A1.z; Bp[7 * 4096] = A1.w;
}

// ---------------- streaming edge kernel: wave per src-sorted edge position ----
// msg[e,o] = C[src,o] + sum_k g[e,k] * B[src-n0, k*64+o]; chunk filter on src.
__global__ __launch_bounds__(256, 8)
void k_edge(const float* __restrict__ g, const float* __restrict__ B,
            const float* __restrict__ Cbuf, const int* __restrict__ ei,
            const int* __restrict__ eid_s, float* __restrict__ msg,
            int n0, int n1) {
    const int pos = blockIdx.x * 4 + (threadIdx.x >> 6);
    const int o = threadIdx.x & 63;
    int e = eid_s[pos];
    int src = ei[e];
    if (src < n0 || src >= n1) return;        // wave-uniform exit
    e = __builtin_amdgcn_readfirstlane(e);
    src = __builtin_amdgcn_readfirstlane(src);
    const float* grow = g + (size_t)e * 64;
    const float* Brow = B + (size_t)(src - n0) * 4096 + o;
    float m0 = Cbuf[(size_t)src * 64 + o];
    float m1 = 0.f, m2 = 0.f, m3 = 0.f;
#pragma unroll
    for (int kk = 0; kk < 4; ++kk) {
        const float4 ga = *(const float4*)(grow + kk * 16);
        const float4 gb = *(const float4*)(grow + kk * 16 + 4);
        const float4 gc = *(const float4*)(grow + kk * 16 + 8);
        const float4 gd = *(const float4*)(grow + kk * 16 + 12);
        const float* Bp = Brow + (size_t)kk * 16 * 64;
        m0 += ga.x * Bp[0 * 64];  m1 += ga.y * Bp[1 * 64];
        m2 += ga.z * Bp[2 * 64];  m3 += ga.w * Bp[3 * 64];
        m0 += gb.x * Bp[4 * 64];  m1 += gb.y * Bp[5 * 64];
        m2 += gb.z * Bp[6 * 64];  m3 += gb.w * Bp[7 * 64];
        m0 += gc.x * Bp[8 * 64];  m1 += gc.y * Bp[9 * 64];
        m2 += gc.z * Bp[10 * 64]; m3 += gc.w * Bp[11 * 64];
        m0 += gd.x * Bp[12 * 64]; m1 += gd.y * Bp[13 * 64];
        m2 += gd.z * Bp[14 * 64]; m3 += gd.w * Bp[15 * 64];
    }
    msg[(size_t)e * 64 + o] = (m0 + m1) + (m2 + m3);
}

// ---------------- gather by dst + root GEMM + silu ----------------
__global__ __launch_bounds__(256)
void k_aggfin(const float* __restrict__ h, const float* __restrict__ msg,
              const int* __restrict__ off2, const int* __restrict__ eid2,
              const float* __restrict__ invd, const float* __restrict__ rw,
              const float* __restrict__ cb, float* __restrict__ hout) {
    __shared__ float Ws[64 * 64];
    __shared__ float As[4 * 64];
    __shared__ int eoff[5];
    const int tid = threadIdx.x;
    for (int idx = tid; idx < 64 * 64; idx += 256) Ws[idx] = rw[idx];
    const int r0 = blockIdx.x * 4;
    As[tid] = h[(size_t)r0 * 64 + tid];
    if (tid < 5) eoff[tid] = off2[r0 + tid];
    __syncthreads();
    const int rr = tid >> 6, c = tid & 63;
    const int r = r0 + rr;
    float a = 0.f;
    for (int p = eoff[rr]; p < eoff[rr + 1]; ++p) {
        const int e = eid2[p];
        a += msg[(size_t)e * 64 + c];
    }
    float s = cb[c] + a * invd[r];
#pragma unroll
    for (int k = 0; k < 64; k++) s += As[rr * 64 + k] * Ws[k * 64 + c];
    hout[(size_t)r * 64 + c] = silu_f(s);
}

// ---------------- global mean pool (accumulate) ----------------
__global__ void k_pool(const float* __restrict__ h, const int* __restrict__ batch,
                       float* __restrict__ hg, float* __restrict__ gcnt) {
    int idx = blockIdx.x * 256 + threadIdx.x;
    if (idx >= NN * 64) return;
    int n = idx >> 6, o = idx & 63;
    int b = batch[n];
    atomicAdd(&hg[b * 64 + o], h[idx]);
    if (o == 0) atomicAdd(&gcnt[b], 1.f);
}

// ---------------- head MLP ----------------
__global__ __launch_bounds__(64)
void k_head(const float* __restrict__ hg, const float* __restrict__ gcnt,
            const float* __restrict__ w1, const float* __restrict__ b1,
            const float* __restrict__ w2, const float* __restrict__ b2,
            float* __restrict__ out) {
    __shared__ float hrow[64];
    const int gidx = blockIdx.x, t = threadIdx.x;
    const float inv = 1.f / fmaxf(gcnt[gidx], 1.f);
    hrow[t] = hg[gidx * 64 + t] * inv;
    __syncthreads();
    float s = b1[t];
#pragma unroll
    for (int k = 0; k < 64; k++) s += hrow[k] * w1[k * 64 + t];
    s = silu_f(s);
    float v = s * w2[t];
#pragma unroll
    for (int d = 32; d > 0; d >>= 1) v += __shfl_down(v, d);
    if (t == 0) out[gidx] = v + b2[0];
}

extern "C" void kernel_launch(void* const* d_in, const int* in_sizes, int n_in,
                              void* d_out, int out_size, void* d_ws, size_t ws_size,
                              hipStream_t stream) {
    const float* x     = (const float*)d_in[0];
    const float* ea    = (const float*)d_in[1];
    const int*   ei    = (const int*)  d_in[2];
    const int*   batch = (const int*)  d_in[3];
    const float* pw    = (const float*)d_in[4];
    const float* pb    = (const float*)d_in[5];
    const float* ew1   = (const float*)d_in[6];
    const float* eb1   = (const float*)d_in[7];
    const float* ew2   = (const float*)d_in[8];
    const float* eb2   = (const float*)d_in[9];
    const float* rw    = (const float*)d_in[10];
    const float* cb    = (const float*)d_in[11];
    const float* hw1   = (const float*)d_in[12];
    const float* hb1   = (const float*)d_in[13];
    const float* hw2   = (const float*)d_in[14];
    const float* hb2   = (const float*)d_in[15];
    float* out = (float*)d_out;

    float* ws = (float*)d_ws;
    size_t off = 0;
    auto alloc = [&](size_t n) {
        float* p = ws + off;
        off += (n + 63) & ~(size_t)63;
        return p;
    };
    float* hA   = alloc((size_t)NN * 64);
    float* hBuf = alloc((size_t)NN * 64);
    float* gbuf = alloc((size_t)NE * 64);
    float* msg  = alloc((size_t)NE * 64);
    float* Cbuf = alloc((size_t)NN * 64);
    float* Bch  = alloc((size_t)BCH_ROWS * 4096);
    float* invd = alloc(NN);
    float* hg   = alloc(64 * 64);
    float* gcnt = alloc(64);
    int* off_s = (int*)alloc(NN + 1);
    int* off_d = (int*)alloc(NN + 1);
    int* cnt_s = (int*)alloc(NN);
    int* cnt_d = (int*)alloc(NN);
    int* cur_s = (int*)alloc(NN);
    int* cur_d = (int*)alloc(NN);
    int* eid_s = (int*)alloc(NE);
    int* eid_d = (int*)alloc(NE);

    hipMemsetAsync(cnt_s, 0, NN * sizeof(int), stream);
    hipMemsetAsync(cnt_d, 0, NN * sizeof(int), stream);
    hipMemsetAsync(hg, 0, 64 * 64 * sizeof(float), stream);
    hipMemsetAsync(gcnt, 0, 64 * sizeof(float), stream);

    k_hist<<<dim3((NE + 255) / 256), dim3(256), 0, stream>>>(ei, cnt_s, cnt_d);
    k_invdeg<<<dim3((NN + 255) / 256), dim3(256), 0, stream>>>(cnt_d, invd);
    k_scan<<<dim3(1), dim3(1024), 0, stream>>>(cnt_s, off_s, cur_s);
    k_scan<<<dim3(1), dim3(1024), 0, stream>>>(cnt_d, off_d, cur_d);
    k_fill<<<dim3((NE + 255) / 256), dim3(256), 0, stream>>>(ei, off_s, cur_s, eid_s);
    k_fill<<<dim3((NE + 255) / 256), dim3(256), 0, stream>>>(ei + NE, off_d, cur_d, eid_d);

    // h = x @ proj_w + proj_b
    k_rowmm<64, false, true><<<dim3(NN / 4), dim3(256), 0, stream>>>(x, pw, pb, hA, NN);

    float* hcur = hA;
    float* hnxt = hBuf;
    for (int l = 0; l < NLAYERS; l++) {
        // g = silu(edge_attr @ w1 + b1)
        k_rowmm<16, true, true><<<dim3(NE / 4), dim3(256), 0, stream>>>(
            ea, ew1 + (size_t)l * EDIM * 64, eb1 + (size_t)l * 64, gbuf, NE);
        // C = h @ b2(reshaped 64x64)
        k_rowmm<64, false, false><<<dim3(NN / 4), dim3(256), 0, stream>>>(
            hcur, eb2 + (size_t)l * 4096, nullptr, Cbuf, NN);
        // chunked: B materialize + edge stream
        for (int c = 0; c < NCHUNKS; ++c) {
            const int n0 = c * NCH;
            const int n1 = (n0 + NCH < NN) ? n0 + NCH : NN;
            k_bgemm<<<dim3(MB_BLOCKS, 16), dim3(256), 0, stream>>>(
                hcur, ew2 + (size_t)l * 64 * 4096, Bch, n0);
            k_edge<<<dim3(NE / 4), dim3(256), 0, stream>>>(
                gbuf, Bch, Cbuf, ei, eid_s, msg, n0, n1);
        }
        k_aggfin<<<dim3(NN / 4), dim3(256), 0, stream>>>(
            hcur, msg, off_d, eid_d, invd, rw + (size_t)l * 64 * 64,
            cb + (size_t)l * 64, hnxt);
        float* t = hcur; hcur = hnxt; hnxt = t;
    }

    k_pool<<<dim3((NN * 64) / 256), dim3(256), 0, stream>>>(hcur, batch, hg, gcnt);
    k_head<<<dim3(NGRAPH), dim3(64), 0, stream>>>(hg, gcnt, hw1, hb1, hw2, hb2, out);
}

// Round 8
// 577.043 us; speedup vs baseline: 3.7674x; 1.3123x over previous
//
#include <hip/hip_runtime.h>
#include <math.h>

#define NN 10000
#define NE 40000
#define NGRAPH 64
#define HID 64
#define EDIM 16
#define NLAYERS 3

__device__ __forceinline__ float silu_f(float x) { return x / (1.f + expf(-x)); }

// ---------------- small row GEMM: out[M][64] = act(A[M][K] @ W[K][64] + bias) ----
template<int K, bool DO_SILU, bool HAS_BIAS>
__global__ __launch_bounds__(256)
void k_rowmm(const float* __restrict__ A, const float* __restrict__ W,
             const float* __restrict__ bias, float* __restrict__ out, int M) {
    __shared__ float Ws[K * 64];
    __shared__ float As[4 * K];
    const int tid = threadIdx.x;
    for (int idx = tid; idx < K * 64; idx += 256) Ws[idx] = W[idx];
    const int r0 = blockIdx.x * 4;
    for (int idx = tid; idx < 4 * K; idx += 256) {
        int r = r0 + idx / K;
        As[idx] = (r < M) ? A[(size_t)r * K + (idx % K)] : 0.f;
    }
    __syncthreads();
    const int rr = tid >> 6, c = tid & 63;
    const int r = r0 + rr;
    if (r >= M) return;
    float s = HAS_BIAS ? bias[c] : 0.f;
#pragma unroll
    for (int k = 0; k < K; k++) s += As[rr * K + k] * Ws[k * 64 + c];
    if (DO_SILU) s = silu_f(s);
    out[(size_t)r * 64 + c] = s;
}

// ---------------- degree histograms (src + dst) ----------------
__global__ void k_hist(const int* __restrict__ ei, int* __restrict__ cnt_s,
                       int* __restrict__ cnt_d) {
    int e = blockIdx.x * 256 + threadIdx.x;
    if (e >= NE) return;
    atomicAdd(&cnt_s[ei[e]], 1);
    atomicAdd(&cnt_d[ei[NE + e]], 1);
}

__global__ void k_invdeg(const int* __restrict__ cnt_d, float* __restrict__ invd) {
    int n = blockIdx.x * 256 + threadIdx.x;
    if (n < NN) {
        int d = cnt_d[n];
        invd[n] = (d > 0) ? 1.f / (float)d : 0.f;
    }
}

// ---------------- single-block exclusive scan over NN counts ----------------
__global__ __launch_bounds__(1024)
void k_scan(const int* __restrict__ cnt, int* __restrict__ off, int* __restrict__ cur) {
    __shared__ int part[1024];
    const int t = threadIdx.x;
    const int CH = (NN + 1023) / 1024;  // 10
    const int base0 = t * CH;
    int s = 0;
    for (int i = 0; i < CH; i++) {
        int idx = base0 + i;
        if (idx < NN) s += cnt[idx];
    }
    part[t] = s;
    __syncthreads();
    for (int d = 1; d < 1024; d <<= 1) {
        int v = (t >= d) ? part[t - d] : 0;
        __syncthreads();
        part[t] += v;
        __syncthreads();
    }
    int run = (t == 0) ? 0 : part[t - 1];
    for (int i = 0; i < CH; i++) {
        int idx = base0 + i;
        if (idx < NN) {
            off[idx] = run;
            run += cnt[idx];
            cur[idx] = 0;
        }
    }
    if (t == 1023) off[NN] = run;
}

__global__ void k_fill(const int* __restrict__ keys, const int* __restrict__ off,
                       int* __restrict__ cur, int* __restrict__ eid) {
    int e = blockIdx.x * 256 + threadIdx.x;
    if (e >= NE) return;
    int s = keys[e];
    int p = atomicAdd(&cur[s], 1);
    eid[off[s] + p] = e;
}

// ---------------- B-chunk GEMM: B[(n-n0), k*64+o] = sum_i h[n,i]*w2[k, i*64+o] ----
__global__ __launch_bounds__(256, 8)
void k_bgemm(const float* __restrict__ h, const float* __restrict__ w2,
             float* __restrict__ B, int n0, int n1) {
    __shared__ float h_s[64 * 8];   // [i][r]
    const int tid = threadIdx.x;
    const int mb = blockIdx.x, nb = blockIdx.y;
    const int row0 = n0 + mb * 8;
#pragma unroll
    for (int idx = tid; idx < 512; idx += 256) {
        const int r = idx >> 6, i = idx & 63;
        const int row = row0 + r;
        h_s[i * 8 + r] = (row < n1) ? h[(size_t)row * 64 + i] : 0.f;
    }
    __syncthreads();

    const int k = nb * 4 + (tid >> 6);
    const int o = tid & 63;
    const float* wp = w2 + (size_t)k * 4096 + o;   // dense 256B wave loads
    float4 A0 = {0.f, 0.f, 0.f, 0.f};
    float4 A1 = {0.f, 0.f, 0.f, 0.f};
#pragma unroll 8
    for (int i = 0; i < 64; ++i) {
        const float w = wp[i * 64];
        const float4 ha = *(const float4*)(h_s + i * 8);       // LDS broadcast
        const float4 hb = *(const float4*)(h_s + i * 8 + 4);
        A0.x += w * ha.x; A0.y += w * ha.y; A0.z += w * ha.z; A0.w += w * ha.w;
        A1.x += w * hb.x; A1.y += w * hb.y; A1.z += w * hb.z; A1.w += w * hb.w;
    }
    float* Bp = B + ((size_t)mb * 8) * 4096 + k * 64 + o;      // dense 256B stores
    Bp[0 * 4096] = A0.x; Bp[1 * 4096] = A0.y;
    Bp[2 * 4096] = A0.z; Bp[3 * 4096] = A0.w;
    Bp[4 * 4096] = A1.x; Bp[5 * 4096] = A1.y;
    Bp[6 * 4096] = A1.z; Bp[7 * 4096] = A1.w;
}

// ---------------- src-grouped edge kernel: wave per source node ----------------
// Wave holds B[src] (64 floats/lane, static regs); per edge: 64 broadcast g reads
// + 64 FMA/lane. B traffic: 16KB per NODE (was per EDGE -> 4x cut).
__global__ __launch_bounds__(256, 1)
void k_edge2(const float* __restrict__ g, const float* __restrict__ B,
             const float* __restrict__ Cbuf, const int* __restrict__ off_s,
             const int* __restrict__ eid_s, float* __restrict__ msg,
             int n0, int nCnt) {
    const int widx = blockIdx.x * 4 + (threadIdx.x >> 6);
    if (widx >= nCnt) return;
    const int n = n0 + widx;
    const int o = threadIdx.x & 63;
    const int p0 = off_s[n], p1 = off_s[n + 1];
    if (p0 == p1) return;                       // no out-edges: skip B load
    const float* Brow = B + (size_t)widx * 4096 + o;
    float b[64];
#pragma unroll
    for (int k = 0; k < 64; ++k) b[k] = Brow[k * 64];   // dense 256B wave loads
    const float cv = Cbuf[(size_t)n * 64 + o];
    for (int p = p0; p < p1; ++p) {
        const int e = __builtin_amdgcn_readfirstlane(eid_s[p]);
        const float* grow = g + (size_t)e * 64;          // uniform -> scalar loads
        float m = cv;
#pragma unroll
        for (int k = 0; k < 64; ++k) m += grow[k] * b[k];
        msg[(size_t)e * 64 + o] = m;
    }
}

// ---------------- gather by dst + root GEMM + silu ----------------
__global__ __launch_bounds__(256)
void k_aggfin(const float* __restrict__ h, const float* __restrict__ msg,
              const int* __restrict__ off2, const int* __restrict__ eid2,
              const float* __restrict__ invd, const float* __restrict__ rw,
              const float* __restrict__ cb, float* __restrict__ hout) {
    __shared__ float Ws[64 * 64];
    __shared__ float As[4 * 64];
    __shared__ int eoff[5];
    const int tid = threadIdx.x;
    for (int idx = tid; idx < 64 * 64; idx += 256) Ws[idx] = rw[idx];
    const int r0 = blockIdx.x * 4;
    As[tid] = h[(size_t)r0 * 64 + tid];
    if (tid < 5) eoff[tid] = off2[r0 + tid];
    __syncthreads();
    const int rr = tid >> 6, c = tid & 63;
    const int r = r0 + rr;
    float a = 0.f;
    for (int p = eoff[rr]; p < eoff[rr + 1]; ++p) {
        const int e = eid2[p];
        a += msg[(size_t)e * 64 + c];
    }
    float s = cb[c] + a * invd[r];
#pragma unroll
    for (int k = 0; k < 64; k++) s += As[rr * 64 + k] * Ws[k * 64 + c];
    hout[(size_t)r * 64 + c] = silu_f(s);
}

// ---------------- fused mean-pool + head MLP (no atomics) ----------------
__global__ __launch_bounds__(256)
void k_poolhead(const float* __restrict__ h, const int* __restrict__ batch,
                const float* __restrict__ w1, const float* __restrict__ b1,
                const float* __restrict__ w2, const float* __restrict__ b2,
                float* __restrict__ out) {
    __shared__ float part[4 * 64];
    __shared__ float hrow[64];
    const int gidx = blockIdx.x;
    const int tid = threadIdx.x;
    const int r = tid >> 6, o = tid & 63;
    // binary search [beg,end) of gidx in sorted batch (uniform across threads)
    int lo = 0, hi = NN;
    while (lo < hi) { int m = (lo + hi) >> 1; if (batch[m] < gidx) lo = m + 1; else hi = m; }
    const int beg = lo;
    hi = NN;
    while (lo < hi) { int m = (lo + hi) >> 1; if (batch[m] < gidx + 1) lo = m + 1; else hi = m; }
    const int end = lo;
    float acc = 0.f;
    for (int n = beg + r; n < end; n += 4) acc += h[(size_t)n * 64 + o];
    part[r * 64 + o] = acc;
    __syncthreads();
    if (tid < 64) {
        const int cnt = end - beg;
        const float inv = (cnt > 0) ? 1.f / (float)cnt : 1.f;
        hrow[tid] = (part[tid] + part[64 + tid] + part[128 + tid] + part[192 + tid]) * inv;
    }
    __syncthreads();
    if (tid < 64) {
        float s = b1[tid];
#pragma unroll
        for (int k = 0; k < 64; ++k) s += hrow[k] * w1[k * 64 + tid];
        s = silu_f(s);
        float v = s * w2[tid];
#pragma unroll
        for (int d = 32; d > 0; d >>= 1) v += __shfl_down(v, d);
        if (tid == 0) out[gidx] = v + b2[0];
    }
}

extern "C" void kernel_launch(void* const* d_in, const int* in_sizes, int n_in,
                              void* d_out, int out_size, void* d_ws, size_t ws_size,
                              hipStream_t stream) {
    const float* x     = (const float*)d_in[0];
    const float* ea    = (const float*)d_in[1];
    const int*   ei    = (const int*)  d_in[2];
    const int*   batch = (const int*)  d_in[3];
    const float* pw    = (const float*)d_in[4];
    const float* pb    = (const float*)d_in[5];
    const float* ew1   = (const float*)d_in[6];
    const float* eb1   = (const float*)d_in[7];
    const float* ew2   = (const float*)d_in[8];
    const float* eb2   = (const float*)d_in[9];
    const float* rw    = (const float*)d_in[10];
    const float* cb    = (const float*)d_in[11];
    const float* hw1   = (const float*)d_in[12];
    const float* hb1   = (const float*)d_in[13];
    const float* hw2   = (const float*)d_in[14];
    const float* hb2   = (const float*)d_in[15];
    float* out = (float*)d_out;

    float* ws = (float*)d_ws;
    size_t off = 0;
    auto alloc = [&](size_t n) {
        float* p = ws + off;
        off += (n + 63) & ~(size_t)63;
        return p;
    };
    float* hA   = alloc((size_t)NN * 64);
    float* hBuf = alloc((size_t)NN * 64);
    float* gbuf = alloc((size_t)NE * 64);
    float* msg  = alloc((size_t)NE * 64);
    float* Cbuf = alloc((size_t)NN * 64);
    float* invd = alloc(NN);
    int* off_s = (int*)alloc(NN + 1);
    int* off_d = (int*)alloc(NN + 1);
    int* cnt_s = (int*)alloc(NN);
    int* cnt_d = (int*)alloc(NN);
    int* cur_s = (int*)alloc(NN);
    int* cur_d = (int*)alloc(NN);
    int* eid_s = (int*)alloc(NE);
    int* eid_d = (int*)alloc(NE);

    // choose chunking for B by available workspace (deterministic: ws_size fixed)
    const size_t fixedFloats = off;
    int nch = 2500;
    {
        auto fits = [&](int rows) {
            size_t padRows = (size_t)((rows + 7) / 8) * 8;
            return (fixedFloats + padRows * 4096 + 64) * sizeof(float) <= ws_size;
        };
        if (fits(10000)) nch = 10000;
        else if (fits(5000)) nch = 5000;
    }
    float* Bch = alloc((size_t)((nch + 7) / 8) * 8 * 4096);

    hipMemsetAsync(cnt_s, 0, NN * sizeof(int), stream);
    hipMemsetAsync(cnt_d, 0, NN * sizeof(int), stream);

    k_hist<<<dim3((NE + 255) / 256), dim3(256), 0, stream>>>(ei, cnt_s, cnt_d);
    k_invdeg<<<dim3((NN + 255) / 256), dim3(256), 0, stream>>>(cnt_d, invd);
    k_scan<<<dim3(1), dim3(1024), 0, stream>>>(cnt_s, off_s, cur_s);
    k_scan<<<dim3(1), dim3(1024), 0, stream>>>(cnt_d, off_d, cur_d);
    k_fill<<<dim3((NE + 255) / 256), dim3(256), 0, stream>>>(ei, off_s, cur_s, eid_s);
    k_fill<<<dim3((NE + 255) / 256), dim3(256), 0, stream>>>(ei + NE, off_d, cur_d, eid_d);

    // h = x @ proj_w + proj_b
    k_rowmm<64, false, true><<<dim3(NN / 4), dim3(256), 0, stream>>>(x, pw, pb, hA, NN);

    float* hcur = hA;
    float* hnxt = hBuf;
    for (int l = 0; l < NLAYERS; l++) {
        // g = silu(edge_attr @ w1 + b1)
        k_rowmm<16, true, true><<<dim3(NE / 4), dim3(256), 0, stream>>>(
            ea, ew1 + (size_t)l * EDIM * 64, eb1 + (size_t)l * 64, gbuf, NE);
        // C = h @ b2(reshaped 64x64)
        k_rowmm<64, false, false><<<dim3(NN / 4), dim3(256), 0, stream>>>(
            hcur, eb2 + (size_t)l * 4096, nullptr, Cbuf, NN);
        for (int n0 = 0; n0 < NN; n0 += nch) {
            const int n1 = (n0 + nch < NN) ? n0 + nch : NN;
            const int nCnt = n1 - n0;
            k_bgemm<<<dim3((nCnt + 7) / 8, 16), dim3(256), 0, stream>>>(
                hcur, ew2 + (size_t)l * 64 * 4096, Bch, n0, n1);
            k_edge2<<<dim3((nCnt + 3) / 4), dim3(256), 0, stream>>>(
                gbuf, Bch, Cbuf, off_s, eid_s, msg, n0, nCnt);
        }
        k_aggfin<<<dim3(NN / 4), dim3(256), 0, stream>>>(
            hcur, msg, off_d, eid_d, invd, rw + (size_t)l * 64 * 64,
            cb + (size_t)l * 64, hnxt);
        float* t = hcur; hcur = hnxt; hnxt = t;
    }

    k_poolhead<<<dim3(NGRAPH), dim3(256), 0, stream>>>(
        hcur, batch, hw1, hb1, hw2, hb2, out);
}

// Round 9
// 556.606 us; speedup vs baseline: 3.9058x; 1.0367x over previous
//
#include <hip/hip_runtime.h>
#include <math.h>

#define NN 10000
#define NE 40000
#define NGRAPH 64
#define HID 64
#define EDIM 16
#define NLAYERS 3
#define MTILE 32

__device__ __forceinline__ float silu_f(float x) { return x / (1.f + expf(-x)); }

// ---------------- small row GEMM: out[M][64] = act(A[M][K] @ W[K][64] + bias) ----
template<int K, bool DO_SILU, bool HAS_BIAS>
__global__ __launch_bounds__(256)
void k_rowmm(const float* __restrict__ A, const float* __restrict__ W,
             const float* __restrict__ bias, float* __restrict__ out, int M) {
    __shared__ float Ws[K * 64];
    __shared__ float As[4 * K];
    const int tid = threadIdx.x;
    for (int idx = tid; idx < K * 64; idx += 256) Ws[idx] = W[idx];
    const int r0 = blockIdx.x * 4;
    for (int idx = tid; idx < 4 * K; idx += 256) {
        int r = r0 + idx / K;
        As[idx] = (r < M) ? A[(size_t)r * K + (idx % K)] : 0.f;
    }
    __syncthreads();
    const int rr = tid >> 6, c = tid & 63;
    const int r = r0 + rr;
    if (r >= M) return;
    float s = HAS_BIAS ? bias[c] : 0.f;
#pragma unroll
    for (int k = 0; k < K; k++) s += As[rr * K + k] * Ws[k * 64 + c];
    if (DO_SILU) s = silu_f(s);
    out[(size_t)r * 64 + c] = s;
}

// ---------------- degree histograms (src + dst) ----------------
__global__ void k_hist(const int* __restrict__ ei, int* __restrict__ cnt_s,
                       int* __restrict__ cnt_d) {
    int e = blockIdx.x * 256 + threadIdx.x;
    if (e >= NE) return;
    atomicAdd(&cnt_s[ei[e]], 1);
    atomicAdd(&cnt_d[ei[NE + e]], 1);
}

__global__ void k_invdeg(const int* __restrict__ cnt_d, float* __restrict__ invd) {
    int n = blockIdx.x * 256 + threadIdx.x;
    if (n < NN) {
        int d = cnt_d[n];
        invd[n] = (d > 0) ? 1.f / (float)d : 0.f;
    }
}

// ---------------- single-block exclusive scan over NN counts ----------------
__global__ __launch_bounds__(1024)
void k_scan(const int* __restrict__ cnt, int* __restrict__ off, int* __restrict__ cur) {
    __shared__ int part[1024];
    const int t = threadIdx.x;
    const int CH = (NN + 1023) / 1024;  // 10
    const int base0 = t * CH;
    int s = 0;
    for (int i = 0; i < CH; i++) {
        int idx = base0 + i;
        if (idx < NN) s += cnt[idx];
    }
    part[t] = s;
    __syncthreads();
    for (int d = 1; d < 1024; d <<= 1) {
        int v = (t >= d) ? part[t - d] : 0;
        __syncthreads();
        part[t] += v;
        __syncthreads();
    }
    int run = (t == 0) ? 0 : part[t - 1];
    for (int i = 0; i < CH; i++) {
        int idx = base0 + i;
        if (idx < NN) {
            off[idx] = run;
            run += cnt[idx];
            cur[idx] = 0;
        }
    }
    if (t == 1023) off[NN] = run;
}

__global__ void k_fill(const int* __restrict__ keys, const int* __restrict__ off,
                       int* __restrict__ cur, int* __restrict__ eid) {
    int e = blockIdx.x * 256 + threadIdx.x;
    if (e >= NE) return;
    int s = keys[e];
    int p = atomicAdd(&cur[s], 1);
    eid[off[s] + p] = e;
}

// ---------------- B-chunk GEMM v2 (MTILE=32): 4x less w2 L2 traffic ----------------
// grid (ceil(n/32), 16); block 256 = 4 waves; thread (k = nb*4 + wave, o = lane),
// owns 32 node-accumulators (constant-indexed, fully unrolled -> registers).
__global__ __launch_bounds__(256, 4)
void k_bgemm(const float* __restrict__ h, const float* __restrict__ w2,
             float* __restrict__ B, int n0, int n1) {
    __shared__ float h_s[64 * 40];   // [i][n], stride 40: float4-aligned
    const int tid = threadIdx.x;
    const int mb = blockIdx.x, nb = blockIdx.y;
    const int row0 = n0 + mb * MTILE;
#pragma unroll
    for (int idx = tid; idx < 64 * MTILE; idx += 256) {
        const int n = idx >> 6, i = idx & 63;
        const int row = row0 + n;
        h_s[i * 40 + n] = (row < n1) ? h[(size_t)row * 64 + i] : 0.f;
    }
    __syncthreads();

    const int k = nb * 4 + (tid >> 6);
    const int o = tid & 63;
    const float* wp = w2 + (size_t)k * 4096 + o;   // dense 256B wave loads
    float acc[MTILE];
#pragma unroll
    for (int j = 0; j < MTILE; ++j) acc[j] = 0.f;
#pragma unroll 2
    for (int i = 0; i < 64; ++i) {
        const float w = wp[i * 64];
        const float* hr = h_s + i * 40;
#pragma unroll
        for (int j8 = 0; j8 < 8; ++j8) {            // LDS broadcast float4 reads
            const float4 hv = *(const float4*)(hr + j8 * 4);
            acc[j8 * 4 + 0] += w * hv.x;
            acc[j8 * 4 + 1] += w * hv.y;
            acc[j8 * 4 + 2] += w * hv.z;
            acc[j8 * 4 + 3] += w * hv.w;
        }
    }
    float* Bp = B + ((size_t)mb * MTILE) * 4096 + k * 64 + o;  // dense 256B stores
#pragma unroll
    for (int j = 0; j < MTILE; ++j) Bp[(size_t)j * 4096] = acc[j];
}

// ---------------- src-grouped edge kernel: wave per source node ----------------
__global__ __launch_bounds__(256, 1)
void k_edge2(const float* __restrict__ g, const float* __restrict__ B,
             const float* __restrict__ Cbuf, const int* __restrict__ off_s,
             const int* __restrict__ eid_s, float* __restrict__ msg,
             int n0, int nCnt) {
    const int widx = blockIdx.x * 4 + (threadIdx.x >> 6);
    if (widx >= nCnt) return;
    const int n = n0 + widx;
    const int o = threadIdx.x & 63;
    const int p0 = off_s[n], p1 = off_s[n + 1];
    if (p0 == p1) return;                       // no out-edges: skip B load
    const float* Brow = B + (size_t)widx * 4096 + o;
    float b[64];
#pragma unroll
    for (int k = 0; k < 64; ++k) b[k] = Brow[k * 64];   // dense 256B wave loads
    const float cv = Cbuf[(size_t)n * 64 + o];
    for (int p = p0; p < p1; ++p) {
        const int e = __builtin_amdgcn_readfirstlane(eid_s[p]);
        const float* grow = g + (size_t)e * 64;          // uniform -> scalar loads
        float m = cv;
#pragma unroll
        for (int k = 0; k < 64; ++k) m += grow[k] * b[k];
        msg[(size_t)e * 64 + o] = m;
    }
}

// ---------------- gather by dst + root GEMM + silu ----------------
__global__ __launch_bounds__(256)
void k_aggfin(const float* __restrict__ h, const float* __restrict__ msg,
              const int* __restrict__ off2, const int* __restrict__ eid2,
              const float* __restrict__ invd, const float* __restrict__ rw,
              const float* __restrict__ cb, float* __restrict__ hout) {
    __shared__ float Ws[64 * 64];
    __shared__ float As[4 * 64];
    __shared__ int eoff[5];
    const int tid = threadIdx.x;
    for (int idx = tid; idx < 64 * 64; idx += 256) Ws[idx] = rw[idx];
    const int r0 = blockIdx.x * 4;
    As[tid] = h[(size_t)r0 * 64 + tid];
    if (tid < 5) eoff[tid] = off2[r0 + tid];
    __syncthreads();
    const int rr = tid >> 6, c = tid & 63;
    const int r = r0 + rr;
    float a = 0.f;
    for (int p = eoff[rr]; p < eoff[rr + 1]; ++p) {
        const int e = eid2[p];
        a += msg[(size_t)e * 64 + c];
    }
    float s = cb[c] + a * invd[r];
#pragma unroll
    for (int k = 0; k < 64; k++) s += As[rr * 64 + k] * Ws[k * 64 + c];
    hout[(size_t)r * 64 + c] = silu_f(s);
}

// ---------------- fused mean-pool + head MLP (no atomics) ----------------
__global__ __launch_bounds__(256)
void k_poolhead(const float* __restrict__ h, const int* __restrict__ batch,
                const float* __restrict__ w1, const float* __restrict__ b1,
                const float* __restrict__ w2, const float* __restrict__ b2,
                float* __restrict__ out) {
    __shared__ float part[4 * 64];
    __shared__ float hrow[64];
    const int gidx = blockIdx.x;
    const int tid = threadIdx.x;
    const int r = tid >> 6, o = tid & 63;
    int lo = 0, hi = NN;
    while (lo < hi) { int m = (lo + hi) >> 1; if (batch[m] < gidx) lo = m + 1; else hi = m; }
    const int beg = lo;
    hi = NN;
    while (lo < hi) { int m = (lo + hi) >> 1; if (batch[m] < gidx + 1) lo = m + 1; else hi = m; }
    const int end = lo;
    float acc = 0.f;
    for (int n = beg + r; n < end; n += 4) acc += h[(size_t)n * 64 + o];
    part[r * 64 + o] = acc;
    __syncthreads();
    if (tid < 64) {
        const int cnt = end - beg;
        const float inv = (cnt > 0) ? 1.f / (float)cnt : 1.f;
        hrow[tid] = (part[tid] + part[64 + tid] + part[128 + tid] + part[192 + tid]) * inv;
    }
    __syncthreads();
    if (tid < 64) {
        float s = b1[tid];
#pragma unroll
        for (int k = 0; k < 64; ++k) s += hrow[k] * w1[k * 64 + tid];
        s = silu_f(s);
        float v = s * w2[tid];
#pragma unroll
        for (int d = 32; d > 0; d >>= 1) v += __shfl_down(v, d);
        if (tid == 0) out[gidx] = v + b2[0];
    }
}

extern "C" void kernel_launch(void* const* d_in, const int* in_sizes, int n_in,
                              void* d_out, int out_size, void* d_ws, size_t ws_size,
                              hipStream_t stream) {
    const float* x     = (const float*)d_in[0];
    const float* ea    = (const float*)d_in[1];
    const int*   ei    = (const int*)  d_in[2];
    const int*   batch = (const int*)  d_in[3];
    const float* pw    = (const float*)d_in[4];
    const float* pb    = (const float*)d_in[5];
    const float* ew1   = (const float*)d_in[6];
    const float* eb1   = (const float*)d_in[7];
    const float* ew2   = (const float*)d_in[8];
    const float* eb2   = (const float*)d_in[9];
    const float* rw    = (const float*)d_in[10];
    const float* cb    = (const float*)d_in[11];
    const float* hw1   = (const float*)d_in[12];
    const float* hb1   = (const float*)d_in[13];
    const float* hw2   = (const float*)d_in[14];
    const float* hb2   = (const float*)d_in[15];
    float* out = (float*)d_out;

    float* ws = (float*)d_ws;
    size_t off = 0;
    auto alloc = [&](size_t n) {
        float* p = ws + off;
        off += (n + 63) & ~(size_t)63;
        return p;
    };
    float* hA   = alloc((size_t)NN * 64);
    float* hBuf = alloc((size_t)NN * 64);
    float* gbuf = alloc((size_t)NE * 64);
    float* msg  = alloc((size_t)NE * 64);
    float* Cbuf = alloc((size_t)NN * 64);
    float* invd = alloc(NN);
    int* off_s = (int*)alloc(NN + 1);
    int* off_d = (int*)alloc(NN + 1);
    int* cnt_s = (int*)alloc(NN);
    int* cnt_d = (int*)alloc(NN);
    int* cur_s = (int*)alloc(NN);
    int* cur_d = (int*)alloc(NN);
    int* eid_s = (int*)alloc(NE);
    int* eid_d = (int*)alloc(NE);

    // choose chunking for B by available workspace (deterministic: ws_size fixed)
    const size_t fixedFloats = off;
    int nch = 2496;
    {
        auto fits = [&](int rows) {
            size_t padRows = (size_t)((rows + MTILE - 1) / MTILE) * MTILE;
            return (fixedFloats + padRows * 4096 + 64) * sizeof(float) <= ws_size;
        };
        if (fits(10000)) nch = 10000;
        else if (fits(5000)) nch = 5000;
    }
    float* Bch = alloc((size_t)((nch + MTILE - 1) / MTILE) * MTILE * 4096);

    hipMemsetAsync(cnt_s, 0, NN * sizeof(int), stream);
    hipMemsetAsync(cnt_d, 0, NN * sizeof(int), stream);

    k_hist<<<dim3((NE + 255) / 256), dim3(256), 0, stream>>>(ei, cnt_s, cnt_d);
    k_invdeg<<<dim3((NN + 255) / 256), dim3(256), 0, stream>>>(cnt_d, invd);
    k_scan<<<dim3(1), dim3(1024), 0, stream>>>(cnt_s, off_s, cur_s);
    k_scan<<<dim3(1), dim3(1024), 0, stream>>>(cnt_d, off_d, cur_d);
    k_fill<<<dim3((NE + 255) / 256), dim3(256), 0, stream>>>(ei, off_s, cur_s, eid_s);
    k_fill<<<dim3((NE + 255) / 256), dim3(256), 0, stream>>>(ei + NE, off_d, cur_d, eid_d);

    // h = x @ proj_w + proj_b
    k_rowmm<64, false, true><<<dim3(NN / 4), dim3(256), 0, stream>>>(x, pw, pb, hA, NN);

    float* hcur = hA;
    float* hnxt = hBuf;
    for (int l = 0; l < NLAYERS; l++) {
        // g = silu(edge_attr @ w1 + b1)
        k_rowmm<16, true, true><<<dim3(NE / 4), dim3(256), 0, stream>>>(
            ea, ew1 + (size_t)l * EDIM * 64, eb1 + (size_t)l * 64, gbuf, NE);
        // C = h @ b2(reshaped 64x64)
        k_rowmm<64, false, false><<<dim3(NN / 4), dim3(256), 0, stream>>>(
            hcur, eb2 + (size_t)l * 4096, nullptr, Cbuf, NN);
        for (int n0 = 0; n0 < NN; n0 += nch) {
            const int n1 = (n0 + nch < NN) ? n0 + nch : NN;
            const int nCnt = n1 - n0;
            k_bgemm<<<dim3((nCnt + MTILE - 1) / MTILE, 16), dim3(256), 0, stream>>>(
                hcur, ew2 + (size_t)l * 64 * 4096, Bch, n0, n1);
            k_edge2<<<dim3((nCnt + 3) / 4), dim3(256), 0, stream>>>(
                gbuf, Bch, Cbuf, off_s, eid_s, msg, n0, nCnt);
        }
        k_aggfin<<<dim3(NN / 4), dim3(256), 0, stream>>>(
            hcur, msg, off_d, eid_d, invd, rw + (size_t)l * 64 * 64,
            cb + (size_t)l * 64, hnxt);
        float* t = hcur; hcur = hnxt; hnxt = t;
    }

    k_poolhead<<<dim3(NGRAPH), dim3(256), 0, stream>>>(
        hcur, batch, hw1, hb1, hw2, hb2, out);
}